// Round 8
// baseline (221.060 us; speedup 1.0000x reference)
//
#include <hip/hip_runtime.h>
#include <hip/hip_bf16.h>
#include <stdint.h>

using bf16 = __hip_bfloat16;
typedef __attribute__((ext_vector_type(8))) short short8;
typedef __attribute__((ext_vector_type(4))) short short4b;
typedef __attribute__((ext_vector_type(4))) float f32x4;
typedef __attribute__((ext_vector_type(4))) unsigned int u32x4;

#if __has_builtin(__builtin_amdgcn_exp2f)
#define EXP2(x) __builtin_amdgcn_exp2f(x)
#else
#define EXP2(x) exp2f(x)
#endif

__device__ __forceinline__ short8 load8(const bf16* p) {
  return *reinterpret_cast<const short8*>(p);
}
__device__ __forceinline__ short4b load4(const bf16* p) {
  return *reinterpret_cast<const short4b*>(p);
}
__device__ __forceinline__ short f2b(float f) {
  return __builtin_bit_cast(short, __float2bfloat16(f));
}
__device__ __forceinline__ unsigned int pk2(float a, float b) {
  return (unsigned int)(unsigned short)f2b(a) |
         ((unsigned int)(unsigned short)f2b(b) << 16);
}
__device__ __forceinline__ void asy16(const bf16* g, bf16* l) {
  __builtin_amdgcn_global_load_lds(
      (const __attribute__((address_space(1))) void*)g,
      (__attribute__((address_space(3))) void*)l, 16, 0, 0);
}

// ---------------- fused prep kernel ----------------
__global__ void k_prep(const float4* __restrict__ x, ushort4* __restrict__ xb,
                       const float* __restrict__ Wq, const float* __restrict__ Wk,
                       const float* __restrict__ Wv, const float* __restrict__ Wo,
                       bf16* __restrict__ Wcat, bf16* __restrict__ Wot,
                       const int4* __restrict__ m4,
                       unsigned long long* __restrict__ bits) {
  int blk = blockIdx.x;
  if (blk < 4096) {
    int i = blk * 256 + threadIdx.x;
    float4 v = x[i];
    ushort4 o;
    o.x = (unsigned short)f2b(v.x);
    o.y = (unsigned short)f2b(v.y);
    o.z = (unsigned short)f2b(v.z);
    o.w = (unsigned short)f2b(v.w);
    xb[i] = o;
  } else if (blk < 8192) {
    int t = (blk - 4096) * 256 + threadIdx.x;
    if (t < 786432) {
      int rr = t >> 9, d = t & 511;
      int which = rr >> 9;
      int hdk = rr & 511, h = hdk >> 6, dk = hdk & 63;
      const float* W = (which == 0) ? Wq : ((which == 1) ? Wk : Wv);
      float v = W[(h * 512 + d) * 64 + dk];
      if (which == 0) v *= 0.18033688011112042f;  // 0.125 * log2(e)
      Wcat[t] = __float2bfloat16(v);
    } else {
      int u = t - 786432;
      int e = u >> 9, hv = u & 511;
      Wot[u] = __float2bfloat16(Wo[hv * 512 + e]);
    }
  } else {
    int i = (blk - 8192) * 256 + threadIdx.x;
    int4 v = m4[i];
    unsigned int nib = (unsigned)(v.x != 0) | ((unsigned)(v.y != 0) << 1) |
                       ((unsigned)(v.z != 0) << 2) | ((unsigned)(v.w != 0) << 3);
    unsigned long long w = (unsigned long long)nib << (4 * (threadIdx.x & 15));
    w |= __shfl_xor(w, 1);
    w |= __shfl_xor(w, 2);
    w |= __shfl_xor(w, 4);
    w |= __shfl_xor(w, 8);
    if ((threadIdx.x & 15) == 0) bits[i >> 4] = w;
  }
}

// ---------------- 128x128 GEMM core, BK=32 double-buffered ----------------
// LDS 32 KB total (As/Bs each 2 x 128x32). 16 stages; XOR swizzle on 16B
// granules (gr ^ row&3). 3 blocks/CU resident -> cross-block overlap hides
// the barrier drain (m97 configuration).
__device__ __forceinline__ void gemm128(const bf16* __restrict__ A,
                                        const bf16* __restrict__ Bt,
                                        bf16* As, bf16* Bs,
                                        int rowBase, int colBase,
                                        f32x4 acc[4][4]) {
  const int tid = threadIdx.x;
  const int lane = tid & 63, w = tid >> 6;
  const int g = lane >> 4, r = lane & 15;

  auto stage = [&](int buf, int s) {
#pragma unroll
    for (int p = 0; p < 2; ++p) {
      int c = p * 256 + tid;                 // 512 chunks of 16B
      int row = c >> 2, gr = c & 3, sg = gr ^ (row & 3);
      asy16(A + (size_t)(rowBase + row) * 512 + s * 32 + sg * 8,
            As + buf * 4096 + c * 8);
    }
#pragma unroll
    for (int p = 0; p < 2; ++p) {
      int c = p * 256 + tid;
      int row = c >> 2, gr = c & 3, sg = gr ^ (row & 3);
      asy16(Bt + (size_t)(colBase + row) * 512 + s * 32 + sg * 8,
            Bs + buf * 4096 + c * 8);
    }
  };

  stage(0, 0);
  int buf = 0;
  const int rbl = (w >> 1) * 64, cbl = (w & 1) * 64;
  for (int s = 0; s < 16; ++s) {
    __syncthreads();
    if (s < 15) stage(buf ^ 1, s + 1);
    const bf16* a0 = As + buf * 4096;
    const bf16* b0 = Bs + buf * 4096;
    short8 af[4], bfr[4];
#pragma unroll
    for (int mt = 0; mt < 4; ++mt) {
      int row = rbl + mt * 16 + r;
      af[mt] = load8(a0 + (row * 4 + (g ^ (row & 3))) * 8);
    }
#pragma unroll
    for (int nt = 0; nt < 4; ++nt) {
      int col = cbl + nt * 16 + r;
      bfr[nt] = load8(b0 + (col * 4 + (g ^ (col & 3))) * 8);
    }
#pragma unroll
    for (int mt = 0; mt < 4; ++mt)
#pragma unroll
      for (int nt = 0; nt < 4; ++nt)
        acc[mt][nt] = __builtin_amdgcn_mfma_f32_16x16x32_bf16(
            af[mt], bfr[nt], acc[mt][nt], 0, 0, 0);
    buf ^= 1;
  }
}

// Fused QKV projection
__global__ __launch_bounds__(256, 3) void k_proj_qkv(
    const bf16* __restrict__ Xb, const bf16* __restrict__ Wcat,
    bf16* __restrict__ Qb, bf16* __restrict__ Kb, bf16* __restrict__ Vt) {
  __shared__ __align__(16) bf16 As[2 * 4096];
  __shared__ __align__(16) bf16 Bs[2 * 4096];
  int rowBase = blockIdx.x * 128, colBase = blockIdx.y * 128;
  f32x4 acc[4][4] = {};
  gemm128(Xb, Wcat, As, Bs, rowBase, colBase, acc);
  const int lane = threadIdx.x & 63, w = threadIdx.x >> 6;
  const int g = lane >> 4, r = lane & 15;
#pragma unroll
  for (int mt = 0; mt < 4; ++mt) {
    int row0 = rowBase + (w >> 1) * 64 + mt * 16 + 4 * g;
    int b = row0 >> 11, n0 = row0 & 2047;
#pragma unroll
    for (int nt = 0; nt < 4; ++nt) {
      int col = colBase + (w & 1) * 64 + nt * 16 + r;
      if (col < 1024) {
        bf16* dst = (col < 512) ? Qb : Kb;
        int hh = (col >> 6) & 7, dk = col & 63;
        bf16* p0 = dst + ((size_t)(b * 8 + hh) * 2048 + n0) * 64 + dk;
#pragma unroll
        for (int rr = 0; rr < 4; ++rr)
          p0[rr * 64] = __float2bfloat16(acc[mt][nt][rr]);
      } else {
        int hdv = col - 1024;
        short4b pkv;
#pragma unroll
        for (int rr = 0; rr < 4; ++rr) pkv[rr] = f2b(acc[mt][nt][rr]);
        *reinterpret_cast<short4b*>(Vt + ((size_t)b * 512 + hdv) * 2048 + n0) = pkv;
      }
    }
  }
}

// Output projection
__global__ __launch_bounds__(256, 2) void k_proj_out(
    const bf16* __restrict__ O, const bf16* __restrict__ Wot,
    float* __restrict__ out) {
  __shared__ __align__(16) bf16 As[2 * 4096];
  __shared__ __align__(16) bf16 Bs[2 * 4096];
  int rowBase = blockIdx.x * 128, colBase = blockIdx.y * 128;
  f32x4 acc[4][4] = {};
  gemm128(O, Wot, As, Bs, rowBase, colBase, acc);
  const int lane = threadIdx.x & 63, w = threadIdx.x >> 6;
  const int g = lane >> 4, r = lane & 15;
#pragma unroll
  for (int mt = 0; mt < 4; ++mt) {
    int row0 = rowBase + (w >> 1) * 64 + mt * 16 + 4 * g;
#pragma unroll
    for (int nt = 0; nt < 4; ++nt) {
      int col = colBase + (w & 1) * 64 + nt * 16 + r;
#pragma unroll
      for (int rr = 0; rr < 4; ++rr)
        out[(size_t)(row0 + rr) * 512 + col] = acc[mt][nt][rr];
    }
  }
}

// ---------------- flash attention, 8 waves x 16 q-rows ----------------
// grid 512 (XCD-swizzled bh x 16 qt-tiles of 128 rows), 512 thr = 8 waves,
// 16 q-rows per wave -> 16 waves/CU (4/SIMD) with UNCHANGED staging per
// block-kt. Double-buffered 32 KB LDS. Max-free exp2 softmax; l via MFMA
// row-sum; shuffle-free epilogue.
__global__ __launch_bounds__(512, 2) void k_attn(const bf16* __restrict__ Q,
    const bf16* __restrict__ K, const bf16* __restrict__ Vt,
    const unsigned long long* __restrict__ MB, bf16* __restrict__ O) {
  const int blin = blockIdx.x;
  const int j = blin >> 3;
  const int bh = (blin & 7) * 4 + (j >> 4);
  const int qt = j & 15;
  const int b = bh >> 3, h = bh & 7;
  const int tid = threadIdx.x;
  const int lane = tid & 63;
  const int wave = tid >> 6;            // 0..7
  const int g = lane >> 4, r = lane & 15;
  const int rx = r & 7;
  const int qbase = qt * 128 + wave * 16;

  __shared__ __align__(16) bf16 Kl[2][64 * 64];
  __shared__ __align__(16) bf16 Vl[2][64 * 64];

  const bf16* Kp = K + (size_t)bh * 2048 * 64;
  const bf16* Vp = Vt + (size_t)bh * 64 * 2048;

  const bf16* Qp = Q + ((size_t)bh * 2048 + qbase + r) * 64;
  short8 qf0 = load8(Qp + g * 8);
  short8 qf1 = load8(Qp + 32 + g * 8);
  const unsigned long long* Mp = MB + ((size_t)b * 2048 + qbase + r) * 32;

  short8 ones;
#pragma unroll
  for (int i = 0; i < 8; ++i) ones[i] = (short)0x3F80;  // bf16 1.0

  f32x4 acc[4] = {};
  f32x4 acc_l = {};

  auto stage = [&](int buf, int kt) {
    const bf16* Kg = Kp + kt * 4096;
    const bf16* Vg = Vp + kt * 64;
    int c = tid;                         // 512 chunks, one per thread
    int row = c >> 3, gr = c & 7, sg = gr ^ (row & 7);
    asy16(Kg + row * 64 + sg * 8, &Kl[buf][0] + c * 8);
    asy16(Vg + (size_t)row * 2048 + sg * 8, &Vl[buf][0] + c * 8);
  };

  stage(0, 0);
  int buf = 0;

  for (int kt = 0; kt < 32; ++kt) {
    __syncthreads();
    if (kt < 31) stage(buf ^ 1, kt + 1);

    unsigned long long mw = Mp[kt];
    const bf16* kl = &Kl[buf][0];
    const bf16* vl = &Vl[buf][0];

    // S^T = K * Q^T  (C: row=kcol at 4g+rr, col=qrow at r)
    f32x4 st[4];
#pragma unroll
    for (int kc = 0; kc < 4; ++kc) {
      const bf16* krow = kl + (kc * 16 + r) * 64;
      short8 kf0 = load8(krow + ((g) ^ rx) * 8);
      short8 kf1 = load8(krow + ((4 + g) ^ rx) * 8);
      f32x4 z = {};
      z = __builtin_amdgcn_mfma_f32_16x16x32_bf16(kf0, qf0, z, 0, 0, 0);
      st[kc] = __builtin_amdgcn_mfma_f32_16x16x32_bf16(kf1, qf1, z, 0, 0, 0);
    }

    // max-free softmax: p = exp2(st) masked to 0
    unsigned ml = (unsigned)mw >> (4 * g);
    unsigned mh = (unsigned)(mw >> 32) >> (4 * g);
    float p[16];
#pragma unroll
    for (int kc = 0; kc < 4; ++kc)
#pragma unroll
      for (int rr = 0; rr < 4; ++rr) {
        float e = EXP2(st[kc][rr]);
        unsigned wsel = (kc & 2) ? mh : ml;
        bool bad = (wsel >> (((kc & 1) << 4) + rr)) & 1u;
        p[kc * 4 + rr] = bad ? 0.f : e;
      }
    u32x4 q0, q1;
#pragma unroll
    for (int i2 = 0; i2 < 4; ++i2) {
      q0[i2] = pk2(p[2 * i2], p[2 * i2 + 1]);
      q1[i2] = pk2(p[8 + 2 * i2], p[8 + 2 * i2 + 1]);
    }
    short8 pa0 = __builtin_bit_cast(short8, q0);
    short8 pa1 = __builtin_bit_cast(short8, q1);

    // l row-sums on the matrix pipe
    acc_l = __builtin_amdgcn_mfma_f32_16x16x32_bf16(pa0, ones, acc_l, 0, 0, 0);
    acc_l = __builtin_amdgcn_mfma_f32_16x16x32_bf16(pa1, ones, acc_l, 0, 0, 0);

    // PV with permuted contraction
#pragma unroll
    for (int dvs = 0; dvs < 4; ++dvs) {
      const bf16* vrow = vl + (dvs * 16 + r) * 64 + (g & 1) * 4;
      short4b v0 = load4(vrow + (((g >> 1)) ^ rx) * 8);
      short4b v1 = load4(vrow + ((2 + (g >> 1)) ^ rx) * 8);
      short4b v2 = load4(vrow + ((4 + (g >> 1)) ^ rx) * 8);
      short4b v3 = load4(vrow + ((6 + (g >> 1)) ^ rx) * 8);
      short8 vb0 = {v0[0], v0[1], v0[2], v0[3], v1[0], v1[1], v1[2], v1[3]};
      short8 vb1 = {v2[0], v2[1], v2[2], v2[3], v3[0], v3[1], v3[2], v3[3]};
      acc[dvs] = __builtin_amdgcn_mfma_f32_16x16x32_bf16(pa0, vb0, acc[dvs], 0, 0, 0);
      acc[dvs] = __builtin_amdgcn_mfma_f32_16x16x32_bf16(pa1, vb1, acc[dvs], 0, 0, 0);
    }
    buf ^= 1;
  }

  // shuffle-free epilogue
  float inv[4];
#pragma unroll
  for (int rr = 0; rr < 4; ++rr)
    inv[rr] = (acc_l[rr] > 0.f) ? 1.f / acc_l[rr] : 0.f;
  bf16* Op = O + ((size_t)b * 2048 + qbase + 4 * g) * 512 + h * 64;
#pragma unroll
  for (int dvs = 0; dvs < 4; ++dvs)
#pragma unroll
    for (int rr = 0; rr < 4; ++rr)
      Op[rr * 512 + dvs * 16 + r] = __float2bfloat16(acc[dvs][rr] * inv[rr]);
}

// ---------------- launch ----------------

extern "C" void kernel_launch(void* const* d_in, const int* in_sizes, int n_in,
                              void* d_out, int out_size, void* d_ws, size_t ws_size,
                              hipStream_t stream) {
  const float* q    = (const float*)d_in[0];
  const int*   mask = (const int*)d_in[1];
  const float* Wq   = (const float*)d_in[2];
  const float* Wk   = (const float*)d_in[3];
  const float* Wv   = (const float*)d_in[4];
  const float* Wo   = (const float*)d_in[5];
  float* out = (float*)d_out;

  char* ws = (char*)d_ws;
  const size_t MB1 = 1024 * 1024;
  bf16* Xb   = (bf16*)(ws + 0);
  bf16* Qb   = (bf16*)(ws + 8 * MB1);
  bf16* Kb   = (bf16*)(ws + 16 * MB1);
  bf16* Vtb  = (bf16*)(ws + 24 * MB1);
  bf16* Ob   = (bf16*)(ws + 32 * MB1);
  unsigned long long* Mbits = (unsigned long long*)(ws + 40 * MB1);
  bf16* Wcat = (bf16*)(ws + 42 * MB1);
  bf16* Wot  = (bf16*)(ws + 42 * MB1 + 1536 * 512 * 2);

  k_prep<<<24576, 256, 0, stream>>>((const float4*)q, (ushort4*)Xb,
                                    Wq, Wk, Wv, Wo, Wcat, Wot,
                                    (const int4*)mask, Mbits);
  k_proj_qkv<<<dim3(64, 12), 256, 0, stream>>>(Xb, Wcat, Qb, Kb, Vtb);
  k_attn<<<512, 512, 0, stream>>>(Qb, Kb, Vtb, Mbits, Ob);
  k_proj_out<<<dim3(64, 4), 256, 0, stream>>>(Ob, Wot, out);
}

// Round 9
// 214.234 us; speedup vs baseline: 1.0319x; 1.0319x over previous
//
#include <hip/hip_runtime.h>
#include <hip/hip_bf16.h>
#include <stdint.h>

using bf16 = __hip_bfloat16;
typedef __attribute__((ext_vector_type(8))) short short8;
typedef __attribute__((ext_vector_type(4))) short short4b;
typedef __attribute__((ext_vector_type(4))) float f32x4;
typedef __attribute__((ext_vector_type(4))) unsigned int u32x4;

#if __has_builtin(__builtin_amdgcn_exp2f)
#define EXP2(x) __builtin_amdgcn_exp2f(x)
#else
#define EXP2(x) exp2f(x)
#endif

__device__ __forceinline__ short8 load8(const bf16* p) {
  return *reinterpret_cast<const short8*>(p);
}
__device__ __forceinline__ short f2b(float f) {
  return __builtin_bit_cast(short, __float2bfloat16(f));
}
__device__ __forceinline__ unsigned int pk2(float a, float b) {
  return (unsigned int)(unsigned short)f2b(a) |
         ((unsigned int)(unsigned short)f2b(b) << 16);
}
__device__ __forceinline__ void asy16(const bf16* g, bf16* l) {
  __builtin_amdgcn_global_load_lds(
      (const __attribute__((address_space(1))) void*)g,
      (__attribute__((address_space(3))) void*)l, 16, 0, 0);
}

// K fragment-order layout (per bh, per kt tile of 64 keys):
//   Kperm[((kc*2+half)*4+g)*128 + r*8 + j] = K[key=kc*16+r][d=half*32+8g+j]
// V fragment-order layout (PV contraction permuted by pi):
//   Vperm[((half*4+dvs)*4+g)*128 + r*8 + j] = V[dv=dvs*16+r][k=half*32+pi(g,j)]
//   pi(g,j) = (j>>2)*16 + 4g + (j&3)
// Both are 4096 elements per (bh,kt); staging to LDS is a linear 8KB copy.

// ---------------- fused prep kernel ----------------
// blocks [0,4096): x f32->bf16 ; [4096,4352): LDS-tiled weight transpose ;
// [4352,20736): mask bit-pack.
__global__ void k_prep(const float4* __restrict__ x, ushort4* __restrict__ xb,
                       const float* __restrict__ Wq, const float* __restrict__ Wk,
                       const float* __restrict__ Wv, const float* __restrict__ Wo,
                       bf16* __restrict__ Wcat, bf16* __restrict__ Wot,
                       const int4* __restrict__ m4,
                       unsigned long long* __restrict__ bits) {
  int blk = blockIdx.x;
  const int tid = threadIdx.x;
  if (blk < 4096) {
    int i = blk * 256 + tid;
    float4 v = x[i];
    ushort4 o;
    o.x = (unsigned short)f2b(v.x);
    o.y = (unsigned short)f2b(v.y);
    o.z = (unsigned short)f2b(v.z);
    o.w = (unsigned short)f2b(v.w);
    xb[i] = o;
  } else if (blk < 4352) {
    int t = blk - 4096;
    __shared__ float T[64][65];
    if (t < 192) {
      // W{q,k,v}[h][512][64] -> Wcat[(which*512+h*64+dk)][d], 64x64 d-tiles
      int which = t >> 6;
      int h = (t >> 3) & 7, dt = t & 7;
      const float* W = (which == 0) ? Wq : ((which == 1) ? Wk : Wv);
#pragma unroll
      for (int p = 0; p < 4; ++p) {
        int row = p * 16 + (tid >> 4);
        float4 v = *(const float4*)(W + (size_t)(h * 512 + dt * 64 + row) * 64 +
                                    (tid & 15) * 4);
        T[row][(tid & 15) * 4 + 0] = v.x;
        T[row][(tid & 15) * 4 + 1] = v.y;
        T[row][(tid & 15) * 4 + 2] = v.z;
        T[row][(tid & 15) * 4 + 3] = v.w;
      }
      __syncthreads();
      float scale = (which == 0) ? 0.18033688011112042f : 1.0f;  // 0.125*log2e
      int jj = tid >> 2, i0 = (tid & 3) * 16;
#pragma unroll
      for (int q = 0; q < 2; ++q) {
        short8 o;
#pragma unroll
        for (int e = 0; e < 8; ++e) o[e] = f2b(T[i0 + q * 8 + e][jj] * scale);
        *(short8*)(Wcat + (size_t)(which * 512 + h * 64 + jj) * 512 + dt * 64 +
                   i0 + q * 8) = o;
      }
    } else {
      // Wo[h][64][512] -> Wot[e][h*64+v], 64x64 e-tiles
      int t2 = t - 192;
      int h = t2 >> 3, et = t2 & 7;
#pragma unroll
      for (int p = 0; p < 4; ++p) {
        int row = p * 16 + (tid >> 4);
        float4 v = *(const float4*)(Wo + (size_t)(h * 64 + row) * 512 + et * 64 +
                                    (tid & 15) * 4);
        T[row][(tid & 15) * 4 + 0] = v.x;
        T[row][(tid & 15) * 4 + 1] = v.y;
        T[row][(tid & 15) * 4 + 2] = v.z;
        T[row][(tid & 15) * 4 + 3] = v.w;
      }
      __syncthreads();
      int jj = tid >> 2, i0 = (tid & 3) * 16;
#pragma unroll
      for (int q = 0; q < 2; ++q) {
        short8 o;
#pragma unroll
        for (int e = 0; e < 8; ++e) o[e] = f2b(T[i0 + q * 8 + e][jj]);
        *(short8*)(Wot + (size_t)(et * 64 + jj) * 512 + h * 64 + i0 + q * 8) = o;
      }
    }
  } else {
    int i = (blk - 4352) * 256 + tid;
    int4 v = m4[i];
    unsigned int nib = (unsigned)(v.x != 0) | ((unsigned)(v.y != 0) << 1) |
                       ((unsigned)(v.z != 0) << 2) | ((unsigned)(v.w != 0) << 3);
    unsigned long long w = (unsigned long long)nib << (4 * (tid & 15));
    w |= __shfl_xor(w, 1);
    w |= __shfl_xor(w, 2);
    w |= __shfl_xor(w, 4);
    w |= __shfl_xor(w, 8);
    if ((tid & 15) == 0) bits[i >> 4] = w;
  }
}

// ---------------- 128x128 GEMM core, BK=32 double-buffered ----------------
__device__ __forceinline__ void gemm128(const bf16* __restrict__ A,
                                        const bf16* __restrict__ Bt,
                                        bf16* As, bf16* Bs,
                                        int rowBase, int colBase,
                                        f32x4 acc[4][4]) {
  const int tid = threadIdx.x;
  const int lane = tid & 63, w = tid >> 6;
  const int g = lane >> 4, r = lane & 15;

  auto stage = [&](int buf, int s) {
#pragma unroll
    for (int p = 0; p < 2; ++p) {
      int c = p * 256 + tid;
      int row = c >> 2, gr = c & 3, sg = gr ^ (row & 3);
      asy16(A + (size_t)(rowBase + row) * 512 + s * 32 + sg * 8,
            As + buf * 4096 + c * 8);
    }
#pragma unroll
    for (int p = 0; p < 2; ++p) {
      int c = p * 256 + tid;
      int row = c >> 2, gr = c & 3, sg = gr ^ (row & 3);
      asy16(Bt + (size_t)(colBase + row) * 512 + s * 32 + sg * 8,
            Bs + buf * 4096 + c * 8);
    }
  };

  stage(0, 0);
  int buf = 0;
  const int rbl = (w >> 1) * 64, cbl = (w & 1) * 64;
  for (int s = 0; s < 16; ++s) {
    __syncthreads();
    if (s < 15) stage(buf ^ 1, s + 1);
    const bf16* a0 = As + buf * 4096;
    const bf16* b0 = Bs + buf * 4096;
    short8 af[4], bfr[4];
#pragma unroll
    for (int mt = 0; mt < 4; ++mt) {
      int row = rbl + mt * 16 + r;
      af[mt] = load8(a0 + (row * 4 + (g ^ (row & 3))) * 8);
    }
#pragma unroll
    for (int nt = 0; nt < 4; ++nt) {
      int col = cbl + nt * 16 + r;
      bfr[nt] = load8(b0 + (col * 4 + (g ^ (col & 3))) * 8);
    }
#pragma unroll
    for (int mt = 0; mt < 4; ++mt)
#pragma unroll
      for (int nt = 0; nt < 4; ++nt)
        acc[mt][nt] = __builtin_amdgcn_mfma_f32_16x16x32_bf16(
            af[mt], bfr[nt], acc[mt][nt], 0, 0, 0);
    buf ^= 1;
  }
}

// Fused QKV projection. Q -> [bh][n][64]; K -> Kperm; V -> Vperm.
__global__ __launch_bounds__(256, 3) void k_proj_qkv(
    const bf16* __restrict__ Xb, const bf16* __restrict__ Wcat,
    bf16* __restrict__ Qb, bf16* __restrict__ Kp, bf16* __restrict__ Vp) {
  __shared__ __align__(16) bf16 As[2 * 4096];
  __shared__ __align__(16) bf16 Bs[2 * 4096];
  int rowBase = blockIdx.x * 128, colBase = blockIdx.y * 128;
  f32x4 acc[4][4] = {};
  gemm128(Xb, Wcat, As, Bs, rowBase, colBase, acc);
  const int lane = threadIdx.x & 63, w = threadIdx.x >> 6;
  const int g = lane >> 4, r = lane & 15;
#pragma unroll
  for (int mt = 0; mt < 4; ++mt) {
    int row0 = rowBase + (w >> 1) * 64 + mt * 16 + 4 * g;
    int b = row0 >> 11, n0 = row0 & 2047;
    int kt = n0 >> 6;
#pragma unroll
    for (int nt = 0; nt < 4; ++nt) {
      int col = colBase + (w & 1) * 64 + nt * 16 + r;
      if (col < 512) {
        int hh = col >> 6, dk = col & 63;
        bf16* p0 = Qb + ((size_t)(b * 8 + hh) * 2048 + n0) * 64 + dk;
#pragma unroll
        for (int rr = 0; rr < 4; ++rr)
          p0[rr * 64] = __float2bfloat16(acc[mt][nt][rr]);
      } else if (col < 1024) {
        int hh = (col >> 6) & 7, dk = col & 63;
        int half = dk >> 5, gk = (dk >> 3) & 3, jj = dk & 7;
        int kr = n0 & 63;
        int kc = kr >> 4, r0 = kr & 15;
        bf16* base = Kp + (size_t)(b * 8 + hh) * 131072 + (size_t)kt * 4096 +
                     ((kc * 2 + half) * 4 + gk) * 128 + jj;
#pragma unroll
        for (int rr = 0; rr < 4; ++rr)
          base[(r0 + rr) * 8] = __float2bfloat16(acc[mt][nt][rr]);
      } else {
        int hdv = col - 1024;
        int hh = hdv >> 6, dv = hdv & 63;
        int dvs = dv >> 4, rv = dv & 15;
        int kcol0 = n0 & 63;
        int half = kcol0 >> 5, gv = (kcol0 >> 2) & 3;
        int j0 = ((kcol0 >> 4) & 1) * 4;
        short4b pkv;
#pragma unroll
        for (int rr = 0; rr < 4; ++rr) pkv[rr] = f2b(acc[mt][nt][rr]);
        *reinterpret_cast<short4b*>(
            Vp + (size_t)(b * 8 + hh) * 131072 + (size_t)kt * 4096 +
            (((half * 4 + dvs) * 4 + gv) * 16 + rv) * 8 + j0) = pkv;
      }
    }
  }
}

// Output projection
__global__ __launch_bounds__(256, 2) void k_proj_out(
    const bf16* __restrict__ O, const bf16* __restrict__ Wot,
    float* __restrict__ out) {
  __shared__ __align__(16) bf16 As[2 * 4096];
  __shared__ __align__(16) bf16 Bs[2 * 4096];
  int rowBase = blockIdx.x * 128, colBase = blockIdx.y * 128;
  f32x4 acc[4][4] = {};
  gemm128(O, Wot, As, Bs, rowBase, colBase, acc);
  const int lane = threadIdx.x & 63, w = threadIdx.x >> 6;
  const int g = lane >> 4, r = lane & 15;
#pragma unroll
  for (int mt = 0; mt < 4; ++mt) {
    int row0 = rowBase + (w >> 1) * 64 + mt * 16 + 4 * g;
#pragma unroll
    for (int nt = 0; nt < 4; ++nt) {
      int col = colBase + (w & 1) * 64 + nt * 16 + r;
#pragma unroll
      for (int rr = 0; rr < 4; ++rr)
        out[(size_t)(row0 + rr) * 512 + col] = acc[mt][nt][rr];
    }
  }
}

// ---------------- flash attention, fragment-order LDS ----------------
// grid 512 (XCD-swizzled bh x 16 qt-tiles of 128 rows), 256 thr = 4 waves,
// 32 q-rows/wave. Triple-buffered LDS staged as a LINEAR copy of the
// fragment-order K/V tiles (all frag reads = contiguous ds_read_b128, zero
// conflicts). QK(kt+1) before softmax(kt); max-free exp2 softmax; l via
// MFMA row-sum; shuffle-free epilogue.
__global__ __launch_bounds__(256, 2) void k_attn(const bf16* __restrict__ Q,
    const bf16* __restrict__ K, const bf16* __restrict__ V,
    const unsigned long long* __restrict__ MB, bf16* __restrict__ O) {
  const int blin = blockIdx.x;
  const int j = blin >> 3;
  const int bh = (blin & 7) * 4 + (j >> 4);
  const int qt = j & 15;
  const int b = bh >> 3, h = bh & 7;
  const int tid = threadIdx.x;
  const int lane = tid & 63;
  const int wave = tid >> 6;
  const int g = lane >> 4, r = lane & 15;
  const int qbase = qt * 128 + wave * 32;

  __shared__ __align__(16) bf16 Kl[3][4096];
  __shared__ __align__(16) bf16 Vl[3][4096];

  const bf16* Kp = K + (size_t)bh * 131072;
  const bf16* Vp = V + (size_t)bh * 131072;

  short8 qf[2][2];
#pragma unroll
  for (int s = 0; s < 2; ++s) {
    const bf16* Qp = Q + ((size_t)bh * 2048 + qbase + s * 16 + r) * 64;
    qf[s][0] = load8(Qp + g * 8);
    qf[s][1] = load8(Qp + 32 + g * 8);
  }
  const unsigned long long* Mp0 = MB + ((size_t)b * 2048 + qbase + r) * 32;
  const unsigned long long* Mp1 = MB + ((size_t)b * 2048 + qbase + 16 + r) * 32;

  short8 ones;
#pragma unroll
  for (int i = 0; i < 8; ++i) ones[i] = (short)0x3F80;  // bf16 1.0

  f32x4 acc[2][4] = {};
  f32x4 acc_l[2] = {};

  auto stage = [&](int buf, int kt) {
    const bf16* Kg = Kp + (size_t)kt * 4096;
    const bf16* Vg = Vp + (size_t)kt * 4096;
#pragma unroll
    for (int p = 0; p < 2; ++p) {
      int c = p * 256 + tid;
      asy16(Kg + c * 8, &Kl[buf][0] + c * 8);
    }
#pragma unroll
    for (int p = 0; p < 2; ++p) {
      int c = p * 256 + tid;
      asy16(Vg + c * 8, &Vl[buf][0] + c * 8);
    }
  };

  auto qk = [&](const bf16* kl, f32x4 stl[4][2]) {
#pragma unroll
    for (int kc = 0; kc < 4; ++kc) {
      short8 kf0 = load8(kl + ((kc * 2 + 0) * 4 + g) * 128 + r * 8);
      short8 kf1 = load8(kl + ((kc * 2 + 1) * 4 + g) * 128 + r * 8);
      f32x4 z0 = {};
      z0 = __builtin_amdgcn_mfma_f32_16x16x32_bf16(kf0, qf[0][0], z0, 0, 0, 0);
      stl[kc][0] = __builtin_amdgcn_mfma_f32_16x16x32_bf16(kf1, qf[0][1], z0, 0, 0, 0);
      f32x4 z1 = {};
      z1 = __builtin_amdgcn_mfma_f32_16x16x32_bf16(kf0, qf[1][0], z1, 0, 0, 0);
      stl[kc][1] = __builtin_amdgcn_mfma_f32_16x16x32_bf16(kf1, qf[1][1], z1, 0, 0, 0);
    }
  };

  stage(0, 0);
  stage(1, 1);
  unsigned long long mw0c = Mp0[0], mw1c = Mp1[0];
  __syncthreads();
  f32x4 st_cur[4][2];
  qk(&Kl[0][0], st_cur);

  int b_cur = 0, b_nxt = 1, b_st = 2;

  for (int kt = 0; kt < 32; ++kt) {
    __syncthreads();
    if (kt < 30) stage(b_st, kt + 2);
    unsigned long long mw0n = 0, mw1n = 0;
    if (kt < 31) { mw0n = Mp0[kt + 1]; mw1n = Mp1[kt + 1]; }

    f32x4 stn[4][2];
    if (kt < 31) qk(&Kl[b_nxt][0], stn);

    // softmax(kt)
    short8 pa[2][2];
#pragma unroll
    for (int s = 0; s < 2; ++s) {
      unsigned long long mw = s ? mw1c : mw0c;
      unsigned ml = (unsigned)mw >> (4 * g);
      unsigned mh = (unsigned)(mw >> 32) >> (4 * g);
      float p[16];
#pragma unroll
      for (int kc = 0; kc < 4; ++kc)
#pragma unroll
        for (int rr = 0; rr < 4; ++rr) {
          float e = EXP2(st_cur[kc][s][rr]);
          unsigned wsel = (kc & 2) ? mh : ml;
          bool bad = (wsel >> (((kc & 1) << 4) + rr)) & 1u;
          p[kc * 4 + rr] = bad ? 0.f : e;
        }
      u32x4 q0, q1;
#pragma unroll
      for (int i2 = 0; i2 < 4; ++i2) {
        q0[i2] = pk2(p[2 * i2], p[2 * i2 + 1]);
        q1[i2] = pk2(p[8 + 2 * i2], p[8 + 2 * i2 + 1]);
      }
      pa[s][0] = __builtin_bit_cast(short8, q0);
      pa[s][1] = __builtin_bit_cast(short8, q1);
      acc_l[s] = __builtin_amdgcn_mfma_f32_16x16x32_bf16(pa[s][0], ones, acc_l[s], 0, 0, 0);
      acc_l[s] = __builtin_amdgcn_mfma_f32_16x16x32_bf16(pa[s][1], ones, acc_l[s], 0, 0, 0);
    }

    // PV (fragment-order V: direct b128 loads)
    const bf16* vl = &Vl[b_cur][0];
#pragma unroll
    for (int dvs = 0; dvs < 4; ++dvs) {
      short8 vb0 = load8(vl + ((0 * 4 + dvs) * 4 + g) * 128 + r * 8);
      short8 vb1 = load8(vl + ((1 * 4 + dvs) * 4 + g) * 128 + r * 8);
#pragma unroll
      for (int s = 0; s < 2; ++s) {
        acc[s][dvs] = __builtin_amdgcn_mfma_f32_16x16x32_bf16(pa[s][0], vb0, acc[s][dvs], 0, 0, 0);
        acc[s][dvs] = __builtin_amdgcn_mfma_f32_16x16x32_bf16(pa[s][1], vb1, acc[s][dvs], 0, 0, 0);
      }
    }

#pragma unroll
    for (int kc = 0; kc < 4; ++kc) {
      st_cur[kc][0] = stn[kc][0];
      st_cur[kc][1] = stn[kc][1];
    }
    mw0c = mw0n;
    mw1c = mw1n;
    int t = b_cur; b_cur = b_nxt; b_nxt = b_st; b_st = t;
  }

  // shuffle-free epilogue
#pragma unroll
  for (int s = 0; s < 2; ++s) {
    float inv[4];
#pragma unroll
    for (int rr = 0; rr < 4; ++rr)
      inv[rr] = (acc_l[s][rr] > 0.f) ? 1.f / acc_l[s][rr] : 0.f;
    bf16* Op = O + ((size_t)b * 2048 + qbase + s * 16 + 4 * g) * 512 + h * 64;
#pragma unroll
    for (int dvs = 0; dvs < 4; ++dvs)
#pragma unroll
      for (int rr = 0; rr < 4; ++rr)
        Op[rr * 512 + dvs * 16 + r] = __float2bfloat16(acc[s][dvs][rr] * inv[rr]);
  }
}

// ---------------- launch ----------------

extern "C" void kernel_launch(void* const* d_in, const int* in_sizes, int n_in,
                              void* d_out, int out_size, void* d_ws, size_t ws_size,
                              hipStream_t stream) {
  const float* q    = (const float*)d_in[0];
  const int*   mask = (const int*)d_in[1];
  const float* Wq   = (const float*)d_in[2];
  const float* Wk   = (const float*)d_in[3];
  const float* Wv   = (const float*)d_in[4];
  const float* Wo   = (const float*)d_in[5];
  float* out = (float*)d_out;

  char* ws = (char*)d_ws;
  const size_t MB1 = 1024 * 1024;
  bf16* Xb   = (bf16*)(ws + 0);          // 8 MB [8192][512]
  bf16* Qb   = (bf16*)(ws + 8 * MB1);    // 8 MB [bh][n][64]
  bf16* Kpm  = (bf16*)(ws + 16 * MB1);   // 8 MB fragment-order K
  bf16* Vpm  = (bf16*)(ws + 24 * MB1);   // 8 MB fragment-order V
  bf16* Ob   = (bf16*)(ws + 32 * MB1);   // 8 MB [bn][512]
  unsigned long long* Mbits = (unsigned long long*)(ws + 40 * MB1);  // 2 MB
  bf16* Wcat = (bf16*)(ws + 42 * MB1);   // 1.5 MB
  bf16* Wot  = (bf16*)(ws + 42 * MB1 + 1536 * 512 * 2);  // 0.5 MB

  k_prep<<<20736, 256, 0, stream>>>((const float4*)q, (ushort4*)Xb,
                                    Wq, Wk, Wv, Wo, Wcat, Wot,
                                    (const int4*)mask, Mbits);
  k_proj_qkv<<<dim3(64, 12), 256, 0, stream>>>(Xb, Wcat, Qb, Kpm, Vpm);
  k_attn<<<512, 256, 0, stream>>>(Qb, Kpm, Vpm, Mbits, Ob);
  k_proj_out<<<dim3(64, 4), 256, 0, stream>>>(Ob, Wot, out);
}